// Round 13
// baseline (1568.350 us; speedup 1.0000x reference)
//
#include <hip/hip_runtime.h>

#define XS 264           // X LDS row stride in bf16 elems (528 B; A b128 reads at 2-way floor)
#define CHUNK_ELEMS 8192 // one 32k x 256n weight chunk, layout [quad][n][8]

typedef __bf16 bf16x8 __attribute__((ext_vector_type(8)));
typedef float f32x4 __attribute__((ext_vector_type(4)));

__device__ __forceinline__ unsigned short f2bf(float f) {
    unsigned int u = __float_as_uint(f);
    u += 0x7fffu + ((u >> 16) & 1u);
    return (unsigned short)(u >> 16);
}

// packed f32->bf16 RNE convert (same rounding as f2bf; R8-verified green).
__device__ __forceinline__ unsigned int cvtpk_bf16(float a, float b) {
    unsigned int r;
    asm("v_cvt_pk_bf16_f32 %0, %1, %2" : "=v"(r) : "v"(a), "v"(b));
    return r;
}

// Workspace layout (bf16 element offsets). Layers 0..3 stored as swizzled chunk
// images: chunk c covers k in [c*32,c*32+32); element (quad,n,j) at offset
// ((quad*256+n)*8+j) holds W[n][c*32+quad*8+j]. 16 consecutive lanes read
// 256 contiguous bytes -> fully coalesced global B-frag loads.
#define OFF0 0        // L0: 5 chunks (K padded 132->160, cols permuted [f1|f2|rel,cell|0])
#define OFF1 40960    // L1: 8 chunks
#define OFF2 106496   // L2
#define OFF3 172032   // L3
#define OFF4 237568   // w4p: 16 x 256 plain (rows 3..15 zero)
#define WTOT 241664
#define NHWC_ELEMS (4 * 4096 * 64)
#define PREP_BLOCKS 944   // WTOT/256
#define TRANS_BLOCKS 512

// Merged prep: blocks [0,944) repack weights; blocks [944,1456) do the
// LDS-tiled NCHW(f32)->NHWC(bf16) transpose. Independent in/out sets.
__global__ __launch_bounds__(256)
void prep_all(const float* __restrict__ w0, const float* __restrict__ w1,
              const float* __restrict__ w2, const float* __restrict__ w3,
              const float* __restrict__ w4, unsigned short* __restrict__ wsp,
              const float* __restrict__ inp1, const float* __restrict__ inp2,
              unsigned short* __restrict__ t1, unsigned short* __restrict__ t2) {
    __shared__ float tile[64][65];   // +1 pad: transposed read is 2-way (free)
    if (blockIdx.x < PREP_BLOCKS) {
        int idx = blockIdx.x * 256 + threadIdx.x;
        if (idx >= WTOT) return;
        unsigned short v = 0;
        if (idx < OFF4) {
            int l, base;
            if (idx < OFF1)      { l = 0; base = OFF0; }
            else if (idx < OFF2) { l = 1; base = OFF1; }
            else if (idx < OFF3) { l = 2; base = OFF2; }
            else                 { l = 3; base = OFF3; }
            int j = idx - base;
            int c = j >> 13;
            int u = j & 8191;
            int flat16 = u >> 3, jj = u & 7;
            int quad = flat16 >> 8, n = flat16 & 255;
            int k = c * 32 + quad * 8 + jj;
            if (l == 0) {
                if (k < 64)       v = f2bf(w0[n * 132 + k]);
                else if (k < 128) v = f2bf(w0[n * 132 + 68 + (k - 64)]);
                else if (k < 132) v = f2bf(w0[n * 132 + 64 + (k - 128)]);
            } else {
                const float* w = (l == 1) ? w1 : (l == 2) ? w2 : w3;
                v = f2bf(w[n * 256 + k]);
            }
        } else {
            int j = idx - OFF4;
            if ((j >> 8) < 3) v = f2bf(w4[j]);
        }
        wsp[idx] = v;
    } else {
        int blk = blockIdx.x - PREP_BLOCKS;  // 0..511
        int tensor = blk >> 8;               // 0..1
        int rem = blk & 255;
        int b = rem >> 6;                    // 0..3
        int f0 = (rem & 63) * 64;            // position-tile base
        const float* src = (tensor ? inp2 : inp1) + (size_t)b * 64 * 4096;
        unsigned short* dst = (tensor ? t2 : t1) + (size_t)b * 4096 * 64;
        int t = threadIdx.x;
        int g = t >> 6;                      // 0..3
        int l = t & 63;                      // 0..63
#pragma unroll
        for (int co = 0; co < 16; ++co) {
            int c = co * 4 + g;
            tile[c][l] = src[(size_t)c * 4096 + f0 + l];
        }
        __syncthreads();
#pragma unroll
        for (int po = 0; po < 16; ++po) {
            int p = po * 4 + g;
            dst[(size_t)(f0 + p) * 64 + l] = f2bf(tile[l][p]);
        }
    }
}

__global__ __launch_bounds__(512, 4)
void liif_mlp(const unsigned short* __restrict__ t1, const unsigned short* __restrict__ t2,
              const float* __restrict__ coord, const float* __restrict__ cell,
              const float* __restrict__ b0, const float* __restrict__ b1,
              const float* __restrict__ b2, const float* __restrict__ b3,
              const float* __restrict__ b4,
              const unsigned short* __restrict__ wsp,
              float* __restrict__ out) {
    __shared__ unsigned short Xs[128 * XS];          // 67,584 B — activations only
    __shared__ float areaS[128];

    const int t = threadIdx.x;
    const int lane = t & 63;
    const int wv = t >> 6;            // 0..7

    // ---------------- gather: X [128 rows x 160 cols], 4 threads per row ----------------
    {
        int lr = t >> 2, sub = t & 3;
        int rg = blockIdx.x * 128 + lr;
        int p = rg >> 2, e = rg & 3;
        int b = p >> 16;
        float c0r = coord[(size_t)p * 2 + 0];
        float c1r = coord[(size_t)p * 2 + 1];
        float vx = (e & 2) ? 1.0f : -1.0f;
        float vy = (e & 1) ? 1.0f : -1.0f;
        const float lo = -1.0f + 1e-6f, hi = 1.0f - 1e-6f;
        float c0 = fminf(fmaxf(c0r + vx * (1.0f / 64.0f) + 1e-6f, lo), hi);
        float c1 = fminf(fmaxf(c1r + vy * (1.0f / 64.0f) + 1e-6f, lo), hi);
        int ih = (int)rintf((c0 + 1.0f) * 32.0f - 0.5f);
        ih = min(63, max(0, ih));
        int iw = (int)rintf((c1 + 1.0f) * 32.0f - 0.5f);
        iw = min(63, max(0, iw));
        int flat = ih * 64 + iw;
        size_t pos = (size_t)b * 4096 + flat;
        const uint4* g1 = (const uint4*)(t1 + pos * 64 + sub * 16);
        const uint4* g2 = (const uint4*)(t2 + pos * 64 + sub * 16);
        uint4 a0 = g1[0], a1 = g1[1];
        uint4 c0v = g2[0], c1v = g2[1];
        uint4* d1 = (uint4*)&Xs[lr * XS + sub * 16];
        uint4* d2 = (uint4*)&Xs[lr * XS + 64 + sub * 16];
        d1[0] = a0; d1[1] = a1;
        d2[0] = c0v; d2[1] = c1v;
        if (sub == 0) {
            float qc0 = -1.0f + (2.0f * ih + 1.0f) * (1.0f / 64.0f);
            float qc1 = -1.0f + (2.0f * iw + 1.0f) * (1.0f / 64.0f);
            float rel0 = (c0r - qc0) * 64.0f;
            float rel1 = (c1r - qc1) * 64.0f;
            Xs[lr * XS + 128] = f2bf(rel0);
            Xs[lr * XS + 129] = f2bf(rel1);
            Xs[lr * XS + 130] = f2bf(cell[(size_t)p * 2 + 0] * 64.0f);
            Xs[lr * XS + 131] = f2bf(cell[(size_t)p * 2 + 1] * 64.0f);
#pragma unroll
            for (int c = 132; c < 160; ++c) Xs[lr * XS + c] = 0;
            areaS[lr] = fabsf(rel0 * rel1) + 1e-9f;
        }
    }
    __syncthreads();

    const int ln15 = lane & 15;
    const int quad = lane >> 4;
    const int mw = wv >> 2;          // row half: rows mw*64 .. +63
    const int nw = wv & 3;           // col group: cols nw*64 .. +63
    const int cb = nw * 64;
    const int rbase = mw * 64;

    const unsigned short* wlbase[4] = {wsp + OFF0, wsp + OFF1, wsp + OFF2, wsp + OFF3};
    const float* bptr[4] = {b0, b1, b2, b3};

#pragma unroll
    for (int l = 0; l < 4; ++l) {
        const int nk = (l == 0) ? 5 : 8;
        // bias-in-accumulator: bias depends only on n = cb + nt*16 + quad*4 + r,
        // so init acc with it (4 f32x4 loads) and drop the add from the epilogue.
        const float* bl = bptr[l];
        f32x4 acc[4][4];
#pragma unroll
        for (int nt = 0; nt < 4; ++nt) {
            f32x4 bv = *(const f32x4*)(bl + cb + nt * 16 + quad * 4);
#pragma unroll
            for (int mt = 0; mt < 4; ++mt)
                acc[mt][nt] = bv;
        }

        // per-lane weight base inside a chunk (coalesced: 16 lanes -> 256 B)
        const unsigned short* bp = wlbase[l] + ((size_t)quad * 256 + cb + ln15) * 8;

        // full-layer weight preload: issue ALL global B-frag loads up front so the
        // k-loop runs pure LDS+MFMA with no vmcnt stall per i-step (loads stay in
        // flight under the first i-steps' MFMAs). Values/order bit-identical to
        // the in-loop-load version; VGPR cost <=128, occupancy is LDS-limited.
        bf16x8 bw[8][4];
#pragma unroll
        for (int i = 0; i < 8; ++i) {
            if (i < nk) {
#pragma unroll
                for (int nt = 0; nt < 4; ++nt)
                    bw[i][nt] = *(const bf16x8*)(bp + (size_t)i * CHUNK_ELEMS + nt * 128);
            }
        }

#pragma unroll
        for (int i = 0; i < nk; ++i) {
            bf16x8 af[4];
#pragma unroll
            for (int mt = 0; mt < 4; ++mt)
                af[mt] = *(const bf16x8*)&Xs[(rbase + mt * 16 + ln15) * XS + i * 32 + quad * 8];
            // swapped operands: D = W·X^T -> lane: "col"(=ln15)=x_row, "row"(=quad*4+reg)=w_n
            __builtin_amdgcn_s_setprio(1);
#pragma unroll
            for (int mt = 0; mt < 4; ++mt)
#pragma unroll
                for (int nt = 0; nt < 4; ++nt)
                    acc[mt][nt] = __builtin_amdgcn_mfma_f32_16x16x32_bf16(
                        bw[i][nt], af[mt], acc[mt][nt], 0, 0, 0);
            __builtin_amdgcn_s_setprio(0);
        }
        __syncthreads();             // all Xs k-input reads for this layer done

        // epilogue: relu + pack via v_cvt_pk_bf16_f32 (RNE = f2bf rounding),
        // stored through the SAME integer-typed 8-B path as the verified base.
#pragma unroll
        for (int mt = 0; mt < 4; ++mt) {
            int row = rbase + mt * 16 + ln15;
#pragma unroll
            for (int nt = 0; nt < 4; ++nt) {
                int col = cb + nt * 16 + quad * 4;
                float v0 = fmaxf(acc[mt][nt][0], 0.0f);
                float v1 = fmaxf(acc[mt][nt][1], 0.0f);
                float v2 = fmaxf(acc[mt][nt][2], 0.0f);
                float v3 = fmaxf(acc[mt][nt][3], 0.0f);
                uint2 pv;
                pv.x = cvtpk_bf16(v0, v1);
                pv.y = cvtpk_bf16(v2, v3);
                *(uint2*)&Xs[row * XS + col] = pv;   // 8 B vector write
            }
        }
        __syncthreads();             // activations visible to all waves
    }

    // ---------------- layer 4: [128 x 256] @ [256 x 16], wave wv owns rows wv*16..+15 ----------------
    {
        f32x4 acc4 = (f32x4){0.f, 0.f, 0.f, 0.f};
        const unsigned short* W4 = wsp + OFF4;
#pragma unroll
        for (int k0 = 0; k0 < 256; k0 += 32) {
            bf16x8 a = *(const bf16x8*)&Xs[(wv * 16 + ln15) * XS + k0 + quad * 8];
            bf16x8 bb = *(const bf16x8*)(W4 + ln15 * 256 + k0 + quad * 8);
            acc4 = __builtin_amdgcn_mfma_f32_16x16x32_bf16(a, bb, acc4, 0, 0, 0);
        }
        int plocal = wv * 4 + quad;          // point within block (0..31), reg r = branch e
        float a0 = areaS[plocal * 4 + 0];
        float a1 = areaS[plocal * 4 + 1];
        float a2 = areaS[plocal * 4 + 2];
        float a3 = areaS[plocal * 4 + 3];
        float tot = a0 + a1 + a2 + a3;
        float r = (acc4[0] * a3 + acc4[1] * a2 + acc4[2] * a1 + acc4[3] * a0) / tot;
        if (ln15 < 3) {
            size_t pg = (size_t)blockIdx.x * 32 + plocal;
            out[pg * 3 + ln15] = r + b4[ln15];
        }
    }
}

extern "C" void kernel_launch(void* const* d_in, const int* in_sizes, int n_in,
                              void* d_out, int out_size, void* d_ws, size_t ws_size,
                              hipStream_t stream) {
    const float* inp1  = (const float*)d_in[0];
    const float* inp2  = (const float*)d_in[1];
    const float* coord = (const float*)d_in[2];
    const float* cell  = (const float*)d_in[3];
    const float* w0 = (const float*)d_in[4];
    const float* b0 = (const float*)d_in[5];
    const float* w1 = (const float*)d_in[6];
    const float* b1 = (const float*)d_in[7];
    const float* w2 = (const float*)d_in[8];
    const float* b2 = (const float*)d_in[9];
    const float* w3 = (const float*)d_in[10];
    const float* b3 = (const float*)d_in[11];
    const float* w4 = (const float*)d_in[12];
    const float* b4 = (const float*)d_in[13];
    float* out = (float*)d_out;

    unsigned short* wsp = (unsigned short*)d_ws;
    unsigned short* t1 = wsp + WTOT;
    unsigned short* t2 = t1 + NHWC_ELEMS;

    prep_all<<<PREP_BLOCKS + TRANS_BLOCKS, 256, 0, stream>>>(w0, w1, w2, w3, w4, wsp,
                                                             inp1, inp2, t1, t2);
    liif_mlp<<<8192, 512, 0, stream>>>(t1, t2, coord, cell,
                                       b0, b1, b2, b3, b4, wsp, out);
}

// Round 15
// 537.469 us; speedup vs baseline: 2.9180x; 2.9180x over previous
//
#include <hip/hip_runtime.h>

#define XS 264           // X LDS row stride in bf16 elems (528 B; A b128 reads at 2-way floor)
#define CHUNK_ELEMS 8192 // one 32k x 256n weight chunk, layout [quad][n][8]

typedef __bf16 bf16x8 __attribute__((ext_vector_type(8)));
typedef float f32x4 __attribute__((ext_vector_type(4)));

__device__ __forceinline__ unsigned short f2bf(float f) {
    unsigned int u = __float_as_uint(f);
    u += 0x7fffu + ((u >> 16) & 1u);
    return (unsigned short)(u >> 16);
}

// packed f32->bf16 RNE convert (same rounding as f2bf; R8-verified green).
__device__ __forceinline__ unsigned int cvtpk_bf16(float a, float b) {
    unsigned int r;
    asm("v_cvt_pk_bf16_f32 %0, %1, %2" : "=v"(r) : "v"(a), "v"(b));
    return r;
}

// Workspace layout (bf16 element offsets). Layers 0..3 stored as swizzled chunk
// images: chunk c covers k in [c*32,c*32+32); element (quad,n,j) at offset
// ((quad*256+n)*8+j) holds W[n][c*32+quad*8+j]. 16 consecutive lanes read
// 256 contiguous bytes -> fully coalesced global B-frag loads.
#define OFF0 0        // L0: 5 chunks (K padded 132->160, cols permuted [f1|f2|rel,cell|0])
#define OFF1 40960    // L1: 8 chunks
#define OFF2 106496   // L2
#define OFF3 172032   // L3
#define OFF4 237568   // w4p: 16 x 256 plain (rows 3..15 zero)
#define WTOT 241664
#define NHWC_ELEMS (4 * 4096 * 64)
#define PREP_BLOCKS 944   // WTOT/256
#define TRANS_BLOCKS 512

// Merged prep: blocks [0,944) repack weights; blocks [944,1456) do the
// LDS-tiled NCHW(f32)->NHWC(bf16) transpose. Independent in/out sets.
__global__ __launch_bounds__(256)
void prep_all(const float* __restrict__ w0, const float* __restrict__ w1,
              const float* __restrict__ w2, const float* __restrict__ w3,
              const float* __restrict__ w4, unsigned short* __restrict__ wsp,
              const float* __restrict__ inp1, const float* __restrict__ inp2,
              unsigned short* __restrict__ t1, unsigned short* __restrict__ t2) {
    __shared__ float tile[64][65];   // +1 pad: transposed read is 2-way (free)
    if (blockIdx.x < PREP_BLOCKS) {
        int idx = blockIdx.x * 256 + threadIdx.x;
        if (idx >= WTOT) return;
        unsigned short v = 0;
        if (idx < OFF4) {
            int l, base;
            if (idx < OFF1)      { l = 0; base = OFF0; }
            else if (idx < OFF2) { l = 1; base = OFF1; }
            else if (idx < OFF3) { l = 2; base = OFF2; }
            else                 { l = 3; base = OFF3; }
            int j = idx - base;
            int c = j >> 13;
            int u = j & 8191;
            int flat16 = u >> 3, jj = u & 7;
            int quad = flat16 >> 8, n = flat16 & 255;
            int k = c * 32 + quad * 8 + jj;
            if (l == 0) {
                if (k < 64)       v = f2bf(w0[n * 132 + k]);
                else if (k < 128) v = f2bf(w0[n * 132 + 68 + (k - 64)]);
                else if (k < 132) v = f2bf(w0[n * 132 + 64 + (k - 128)]);
            } else {
                const float* w = (l == 1) ? w1 : (l == 2) ? w2 : w3;
                v = f2bf(w[n * 256 + k]);
            }
        } else {
            int j = idx - OFF4;
            if ((j >> 8) < 3) v = f2bf(w4[j]);
        }
        wsp[idx] = v;
    } else {
        int blk = blockIdx.x - PREP_BLOCKS;  // 0..511
        int tensor = blk >> 8;               // 0..1
        int rem = blk & 255;
        int b = rem >> 6;                    // 0..3
        int f0 = (rem & 63) * 64;            // position-tile base
        const float* src = (tensor ? inp2 : inp1) + (size_t)b * 64 * 4096;
        unsigned short* dst = (tensor ? t2 : t1) + (size_t)b * 4096 * 64;
        int t = threadIdx.x;
        int g = t >> 6;                      // 0..3
        int l = t & 63;                      // 0..63
#pragma unroll
        for (int co = 0; co < 16; ++co) {
            int c = co * 4 + g;
            tile[c][l] = src[(size_t)c * 4096 + f0 + l];
        }
        __syncthreads();
#pragma unroll
        for (int po = 0; po < 16; ++po) {
            int p = po * 4 + g;
            dst[(size_t)(f0 + p) * 64 + l] = f2bf(tile[l][p]);
        }
    }
}

__global__ __launch_bounds__(512, 4)
void liif_mlp(const unsigned short* __restrict__ t1, const unsigned short* __restrict__ t2,
              const float* __restrict__ coord, const float* __restrict__ cell,
              const float* __restrict__ b0, const float* __restrict__ b1,
              const float* __restrict__ b2, const float* __restrict__ b3,
              const float* __restrict__ b4,
              const unsigned short* __restrict__ wsp,
              float* __restrict__ out) {
    __shared__ unsigned short Xs[128 * XS];          // 67,584 B — activations only
    __shared__ float areaS[128];

    const int t = threadIdx.x;
    const int lane = t & 63;
    const int wv = t >> 6;            // 0..7

    // ---------------- gather: X [128 rows x 160 cols], 4 threads per row ----------------
    {
        int lr = t >> 2, sub = t & 3;
        int rg = blockIdx.x * 128 + lr;
        int p = rg >> 2, e = rg & 3;
        int b = p >> 16;
        float c0r = coord[(size_t)p * 2 + 0];
        float c1r = coord[(size_t)p * 2 + 1];
        float vx = (e & 2) ? 1.0f : -1.0f;
        float vy = (e & 1) ? 1.0f : -1.0f;
        const float lo = -1.0f + 1e-6f, hi = 1.0f - 1e-6f;
        float c0 = fminf(fmaxf(c0r + vx * (1.0f / 64.0f) + 1e-6f, lo), hi);
        float c1 = fminf(fmaxf(c1r + vy * (1.0f / 64.0f) + 1e-6f, lo), hi);
        int ih = (int)rintf((c0 + 1.0f) * 32.0f - 0.5f);
        ih = min(63, max(0, ih));
        int iw = (int)rintf((c1 + 1.0f) * 32.0f - 0.5f);
        iw = min(63, max(0, iw));
        int flat = ih * 64 + iw;
        size_t pos = (size_t)b * 4096 + flat;
        const uint4* g1 = (const uint4*)(t1 + pos * 64 + sub * 16);
        const uint4* g2 = (const uint4*)(t2 + pos * 64 + sub * 16);
        uint4 a0 = g1[0], a1 = g1[1];
        uint4 c0v = g2[0], c1v = g2[1];
        uint4* d1 = (uint4*)&Xs[lr * XS + sub * 16];
        uint4* d2 = (uint4*)&Xs[lr * XS + 64 + sub * 16];
        d1[0] = a0; d1[1] = a1;
        d2[0] = c0v; d2[1] = c1v;
        if (sub == 0) {
            float qc0 = -1.0f + (2.0f * ih + 1.0f) * (1.0f / 64.0f);
            float qc1 = -1.0f + (2.0f * iw + 1.0f) * (1.0f / 64.0f);
            float rel0 = (c0r - qc0) * 64.0f;
            float rel1 = (c1r - qc1) * 64.0f;
            Xs[lr * XS + 128] = f2bf(rel0);
            Xs[lr * XS + 129] = f2bf(rel1);
            Xs[lr * XS + 130] = f2bf(cell[(size_t)p * 2 + 0] * 64.0f);
            Xs[lr * XS + 131] = f2bf(cell[(size_t)p * 2 + 1] * 64.0f);
#pragma unroll
            for (int c = 132; c < 160; ++c) Xs[lr * XS + c] = 0;
            areaS[lr] = fabsf(rel0 * rel1) + 1e-9f;
        }
    }
    __syncthreads();

    const int ln15 = lane & 15;
    const int quad = lane >> 4;
    const int mw = wv >> 2;          // row half: rows mw*64 .. +63
    const int nw = wv & 3;           // col group: cols nw*64 .. +63
    const int cb = nw * 64;
    const int rbase = mw * 64;

    const unsigned short* wlbase[4] = {wsp + OFF0, wsp + OFF1, wsp + OFF2, wsp + OFF3};
    const float* bptr[4] = {b0, b1, b2, b3};

#pragma unroll
    for (int l = 0; l < 4; ++l) {
        const int nk = (l == 0) ? 5 : 8;
        // bias-in-accumulator: bias depends only on n = cb + nt*16 + quad*4 + r,
        // so init acc with it (4 f32x4 loads) and drop the add from the epilogue.
        const float* bl = bptr[l];
        f32x4 acc[4][4];
#pragma unroll
        for (int nt = 0; nt < 4; ++nt) {
            f32x4 bv = *(const f32x4*)(bl + cb + nt * 16 + quad * 4);
#pragma unroll
            for (int mt = 0; mt < 4; ++mt)
                acc[mt][nt] = bv;
        }

        // per-lane weight base inside a chunk (coalesced: 16 lanes -> 256 B)
        const unsigned short* bp = wlbase[l] + ((size_t)quad * 256 + cb + ln15) * 8;

#pragma unroll
        for (int i = 0; i < nk; ++i) {
            bf16x8 bfr[4], af[4];
#pragma unroll
            for (int nt = 0; nt < 4; ++nt)
                bfr[nt] = *(const bf16x8*)(bp + (size_t)i * CHUNK_ELEMS + nt * 128);
#pragma unroll
            for (int mt = 0; mt < 4; ++mt)
                af[mt] = *(const bf16x8*)&Xs[(rbase + mt * 16 + ln15) * XS + i * 32 + quad * 8];
            // swapped operands: D = W·X^T -> lane: "col"(=ln15)=x_row, "row"(=quad*4+reg)=w_n
#pragma unroll
            for (int mt = 0; mt < 4; ++mt)
#pragma unroll
                for (int nt = 0; nt < 4; ++nt)
                    acc[mt][nt] = __builtin_amdgcn_mfma_f32_16x16x32_bf16(
                        bfr[nt], af[mt], acc[mt][nt], 0, 0, 0);
        }
        __syncthreads();             // all Xs k-input reads for this layer done

        // epilogue: relu + pack via v_cvt_pk_bf16_f32 (RNE = f2bf rounding),
        // stored through the SAME integer-typed 8-B path as the verified base.
#pragma unroll
        for (int mt = 0; mt < 4; ++mt) {
            int row = rbase + mt * 16 + ln15;
#pragma unroll
            for (int nt = 0; nt < 4; ++nt) {
                int col = cb + nt * 16 + quad * 4;
                float v0 = fmaxf(acc[mt][nt][0], 0.0f);
                float v1 = fmaxf(acc[mt][nt][1], 0.0f);
                float v2 = fmaxf(acc[mt][nt][2], 0.0f);
                float v3 = fmaxf(acc[mt][nt][3], 0.0f);
                uint2 pv;
                pv.x = cvtpk_bf16(v0, v1);
                pv.y = cvtpk_bf16(v2, v3);
                *(uint2*)&Xs[row * XS + col] = pv;   // 8 B vector write
            }
        }
        __syncthreads();             // activations visible to all waves
    }

    // ---------------- layer 4: [128 x 256] @ [256 x 16], wave wv owns rows wv*16..+15 ----------------
    {
        f32x4 acc4 = (f32x4){0.f, 0.f, 0.f, 0.f};
        const unsigned short* W4 = wsp + OFF4;
#pragma unroll
        for (int k0 = 0; k0 < 256; k0 += 32) {
            bf16x8 a = *(const bf16x8*)&Xs[(wv * 16 + ln15) * XS + k0 + quad * 8];
            bf16x8 bb = *(const bf16x8*)(W4 + ln15 * 256 + k0 + quad * 8);
            acc4 = __builtin_amdgcn_mfma_f32_16x16x32_bf16(a, bb, acc4, 0, 0, 0);
        }
        int plocal = wv * 4 + quad;          // point within block (0..31), reg r = branch e
        float a0 = areaS[plocal * 4 + 0];
        float a1 = areaS[plocal * 4 + 1];
        float a2 = areaS[plocal * 4 + 2];
        float a3 = areaS[plocal * 4 + 3];
        float tot = a0 + a1 + a2 + a3;
        float r = (acc4[0] * a3 + acc4[1] * a2 + acc4[2] * a1 + acc4[3] * a0) / tot;
        if (ln15 < 3) {
            size_t pg = (size_t)blockIdx.x * 32 + plocal;
            out[pg * 3 + ln15] = r + b4[ln15];
        }
    }
}

extern "C" void kernel_launch(void* const* d_in, const int* in_sizes, int n_in,
                              void* d_out, int out_size, void* d_ws, size_t ws_size,
                              hipStream_t stream) {
    const float* inp1  = (const float*)d_in[0];
    const float* inp2  = (const float*)d_in[1];
    const float* coord = (const float*)d_in[2];
    const float* cell  = (const float*)d_in[3];
    const float* w0 = (const float*)d_in[4];
    const float* b0 = (const float*)d_in[5];
    const float* w1 = (const float*)d_in[6];
    const float* b1 = (const float*)d_in[7];
    const float* w2 = (const float*)d_in[8];
    const float* b2 = (const float*)d_in[9];
    const float* w3 = (const float*)d_in[10];
    const float* b3 = (const float*)d_in[11];
    const float* w4 = (const float*)d_in[12];
    const float* b4 = (const float*)d_in[13];
    float* out = (float*)d_out;

    unsigned short* wsp = (unsigned short*)d_ws;
    unsigned short* t1 = wsp + WTOT;
    unsigned short* t2 = t1 + NHWC_ELEMS;

    prep_all<<<PREP_BLOCKS + TRANS_BLOCKS, 256, 0, stream>>>(w0, w1, w2, w3, w4, wsp,
                                                             inp1, inp2, t1, t2);
    liif_mlp<<<8192, 512, 0, stream>>>(t1, t2, coord, cell,
                                       b0, b1, b2, b3, b4, wsp, out);
}

// Round 16
// 513.728 us; speedup vs baseline: 3.0529x; 1.0462x over previous
//
#include <hip/hip_runtime.h>

#define XS 264           // X LDS row stride in bf16 elems (528 B; A b128 reads at 2-way floor)
#define CHUNK_ELEMS 8192 // one 32k x 256n weight chunk, layout [quad][n][8]

typedef __bf16 bf16x8 __attribute__((ext_vector_type(8)));
typedef float f32x4 __attribute__((ext_vector_type(4)));

__device__ __forceinline__ unsigned short f2bf(float f) {
    unsigned int u = __float_as_uint(f);
    u += 0x7fffu + ((u >> 16) & 1u);
    return (unsigned short)(u >> 16);
}

// packed f32->bf16 RNE convert (same rounding as f2bf; R8-verified green).
__device__ __forceinline__ unsigned int cvtpk_bf16(float a, float b) {
    unsigned int r;
    asm("v_cvt_pk_bf16_f32 %0, %1, %2" : "=v"(r) : "v"(a), "v"(b));
    return r;
}

// Workspace layout (bf16 element offsets). Layers 0..3 stored as swizzled chunk
// images: chunk c covers k in [c*32,c*32+32); element (quad,n,j) at offset
// ((quad*256+n)*8+j) holds W[n][c*32+quad*8+j]. 16 consecutive lanes read
// 256 contiguous bytes -> fully coalesced global B-frag loads.
#define OFF0 0        // L0: 5 chunks (K padded 132->160, cols permuted [f1|f2|rel,cell|0])
#define OFF1 40960    // L1: 8 chunks
#define OFF2 106496   // L2
#define OFF3 172032   // L3
#define OFF4 237568   // w4p: 16 x 256 plain (rows 3..15 zero)
#define WTOT 241664
#define NHWC_ELEMS (4 * 4096 * 64)
#define PREP_BLOCKS 944   // WTOT/256
#define TRANS_BLOCKS 512

// Merged prep: blocks [0,944) repack weights; blocks [944,1456) do the
// LDS-tiled NCHW(f32)->NHWC(bf16) transpose. Independent in/out sets.
__global__ __launch_bounds__(256)
void prep_all(const float* __restrict__ w0, const float* __restrict__ w1,
              const float* __restrict__ w2, const float* __restrict__ w3,
              const float* __restrict__ w4, unsigned short* __restrict__ wsp,
              const float* __restrict__ inp1, const float* __restrict__ inp2,
              unsigned short* __restrict__ t1, unsigned short* __restrict__ t2) {
    __shared__ float tile[64][65];   // +1 pad: transposed read is 2-way (free)
    if (blockIdx.x < PREP_BLOCKS) {
        int idx = blockIdx.x * 256 + threadIdx.x;
        if (idx >= WTOT) return;
        unsigned short v = 0;
        if (idx < OFF4) {
            int l, base;
            if (idx < OFF1)      { l = 0; base = OFF0; }
            else if (idx < OFF2) { l = 1; base = OFF1; }
            else if (idx < OFF3) { l = 2; base = OFF2; }
            else                 { l = 3; base = OFF3; }
            int j = idx - base;
            int c = j >> 13;
            int u = j & 8191;
            int flat16 = u >> 3, jj = u & 7;
            int quad = flat16 >> 8, n = flat16 & 255;
            int k = c * 32 + quad * 8 + jj;
            if (l == 0) {
                if (k < 64)       v = f2bf(w0[n * 132 + k]);
                else if (k < 128) v = f2bf(w0[n * 132 + 68 + (k - 64)]);
                else if (k < 132) v = f2bf(w0[n * 132 + 64 + (k - 128)]);
            } else {
                const float* w = (l == 1) ? w1 : (l == 2) ? w2 : w3;
                v = f2bf(w[n * 256 + k]);
            }
        } else {
            int j = idx - OFF4;
            if ((j >> 8) < 3) v = f2bf(w4[j]);
        }
        wsp[idx] = v;
    } else {
        int blk = blockIdx.x - PREP_BLOCKS;  // 0..511
        int tensor = blk >> 8;               // 0..1
        int rem = blk & 255;
        int b = rem >> 6;                    // 0..3
        int f0 = (rem & 63) * 64;            // position-tile base
        const float* src = (tensor ? inp2 : inp1) + (size_t)b * 64 * 4096;
        unsigned short* dst = (tensor ? t2 : t1) + (size_t)b * 4096 * 64;
        int t = threadIdx.x;
        int g = t >> 6;                      // 0..3
        int l = t & 63;                      // 0..63
#pragma unroll
        for (int co = 0; co < 16; ++co) {
            int c = co * 4 + g;
            tile[c][l] = src[(size_t)c * 4096 + f0 + l];
        }
        __syncthreads();
#pragma unroll
        for (int po = 0; po < 16; ++po) {
            int p = po * 4 + g;
            dst[(size_t)(f0 + p) * 64 + l] = f2bf(tile[l][p]);
        }
    }
}

__global__ __launch_bounds__(512, 4)
void liif_mlp(const unsigned short* __restrict__ t1, const unsigned short* __restrict__ t2,
              const float* __restrict__ coord, const float* __restrict__ cell,
              const float* __restrict__ b0, const float* __restrict__ b1,
              const float* __restrict__ b2, const float* __restrict__ b3,
              const float* __restrict__ b4,
              const unsigned short* __restrict__ wsp,
              float* __restrict__ out) {
    __shared__ unsigned short Xs[128 * XS];          // 67,584 B — activations only
    __shared__ float areaS[128];

    const int t = threadIdx.x;
    const int lane = t & 63;
    const int wv = t >> 6;            // 0..7

    // ---------------- gather: X [128 rows x 160 cols], 4 threads per row ----------------
    {
        int lr = t >> 2, sub = t & 3;
        int rg = blockIdx.x * 128 + lr;
        int p = rg >> 2, e = rg & 3;
        int b = p >> 16;
        float c0r = coord[(size_t)p * 2 + 0];
        float c1r = coord[(size_t)p * 2 + 1];
        float vx = (e & 2) ? 1.0f : -1.0f;
        float vy = (e & 1) ? 1.0f : -1.0f;
        const float lo = -1.0f + 1e-6f, hi = 1.0f - 1e-6f;
        float c0 = fminf(fmaxf(c0r + vx * (1.0f / 64.0f) + 1e-6f, lo), hi);
        float c1 = fminf(fmaxf(c1r + vy * (1.0f / 64.0f) + 1e-6f, lo), hi);
        int ih = (int)rintf((c0 + 1.0f) * 32.0f - 0.5f);
        ih = min(63, max(0, ih));
        int iw = (int)rintf((c1 + 1.0f) * 32.0f - 0.5f);
        iw = min(63, max(0, iw));
        int flat = ih * 64 + iw;
        size_t pos = (size_t)b * 4096 + flat;
        const uint4* g1 = (const uint4*)(t1 + pos * 64 + sub * 16);
        const uint4* g2 = (const uint4*)(t2 + pos * 64 + sub * 16);
        uint4 a0 = g1[0], a1 = g1[1];
        uint4 c0v = g2[0], c1v = g2[1];
        uint4* d1 = (uint4*)&Xs[lr * XS + sub * 16];
        uint4* d2 = (uint4*)&Xs[lr * XS + 64 + sub * 16];
        d1[0] = a0; d1[1] = a1;
        d2[0] = c0v; d2[1] = c1v;
        if (sub == 0) {
            float qc0 = -1.0f + (2.0f * ih + 1.0f) * (1.0f / 64.0f);
            float qc1 = -1.0f + (2.0f * iw + 1.0f) * (1.0f / 64.0f);
            float rel0 = (c0r - qc0) * 64.0f;
            float rel1 = (c1r - qc1) * 64.0f;
            Xs[lr * XS + 128] = f2bf(rel0);
            Xs[lr * XS + 129] = f2bf(rel1);
            Xs[lr * XS + 130] = f2bf(cell[(size_t)p * 2 + 0] * 64.0f);
            Xs[lr * XS + 131] = f2bf(cell[(size_t)p * 2 + 1] * 64.0f);
#pragma unroll
            for (int c = 132; c < 160; ++c) Xs[lr * XS + c] = 0;
            areaS[lr] = fabsf(rel0 * rel1) + 1e-9f;
        }
    }
    __syncthreads();

    const int ln15 = lane & 15;
    const int quad = lane >> 4;
    const int mw = wv >> 2;          // row half: rows mw*64 .. +63
    const int nw = wv & 3;           // col group: cols nw*64 .. +63
    const int cb = nw * 64;
    const int rbase = mw * 64;

    const unsigned short* wlbase[4] = {wsp + OFF0, wsp + OFF1, wsp + OFF2, wsp + OFF3};
    const float* bptr[4] = {b0, b1, b2, b3};

#pragma unroll
    for (int l = 0; l < 4; ++l) {
        const int nk = (l == 0) ? 5 : 8;
        // bias-in-accumulator: bias depends only on n = cb + nt*16 + quad*4 + r,
        // so init acc with it (4 f32x4 loads) and drop the add from the epilogue.
        const float* bl = bptr[l];
        f32x4 acc[4][4];
#pragma unroll
        for (int nt = 0; nt < 4; ++nt) {
            f32x4 bv = *(const f32x4*)(bl + cb + nt * 16 + quad * 4);
#pragma unroll
            for (int mt = 0; mt < 4; ++mt)
                acc[mt][nt] = bv;
        }

        // per-lane weight base inside a chunk (coalesced: 16 lanes -> 256 B)
        const unsigned short* bp = wlbase[l] + ((size_t)quad * 256 + cb + ln15) * 8;

#pragma unroll
        for (int i = 0; i < nk; ++i) {
            bf16x8 bfr[4], af[4];
#pragma unroll
            for (int nt = 0; nt < 4; ++nt)
                bfr[nt] = *(const bf16x8*)(bp + (size_t)i * CHUNK_ELEMS + nt * 128);
#pragma unroll
            for (int mt = 0; mt < 4; ++mt)
                af[mt] = *(const bf16x8*)&Xs[(rbase + mt * 16 + ln15) * XS + i * 32 + quad * 8];
            // swapped operands: D = W·X^T -> lane: "col"(=ln15)=x_row, "row"(=quad*4+reg)=w_n
            __builtin_amdgcn_s_setprio(1);
#pragma unroll
            for (int mt = 0; mt < 4; ++mt)
#pragma unroll
                for (int nt = 0; nt < 4; ++nt)
                    acc[mt][nt] = __builtin_amdgcn_mfma_f32_16x16x32_bf16(
                        bfr[nt], af[mt], acc[mt][nt], 0, 0, 0);
            __builtin_amdgcn_s_setprio(0);
        }
        __syncthreads();             // all Xs k-input reads for this layer done

        // epilogue: relu + pack via v_cvt_pk_bf16_f32 (RNE = f2bf rounding),
        // stored through the SAME integer-typed 8-B path as the verified base.
#pragma unroll
        for (int mt = 0; mt < 4; ++mt) {
            int row = rbase + mt * 16 + ln15;
#pragma unroll
            for (int nt = 0; nt < 4; ++nt) {
                int col = cb + nt * 16 + quad * 4;
                float v0 = fmaxf(acc[mt][nt][0], 0.0f);
                float v1 = fmaxf(acc[mt][nt][1], 0.0f);
                float v2 = fmaxf(acc[mt][nt][2], 0.0f);
                float v3 = fmaxf(acc[mt][nt][3], 0.0f);
                uint2 pv;
                pv.x = cvtpk_bf16(v0, v1);
                pv.y = cvtpk_bf16(v2, v3);
                *(uint2*)&Xs[row * XS + col] = pv;   // 8 B vector write
            }
        }
        __syncthreads();             // activations visible to all waves
    }

    // ---------------- layer 4: [128 x 256] @ [256 x 16], wave wv owns rows wv*16..+15 ----------------
    {
        f32x4 acc4 = (f32x4){0.f, 0.f, 0.f, 0.f};
        const unsigned short* W4 = wsp + OFF4;
#pragma unroll
        for (int k0 = 0; k0 < 256; k0 += 32) {
            bf16x8 a = *(const bf16x8*)&Xs[(wv * 16 + ln15) * XS + k0 + quad * 8];
            bf16x8 bb = *(const bf16x8*)(W4 + ln15 * 256 + k0 + quad * 8);
            acc4 = __builtin_amdgcn_mfma_f32_16x16x32_bf16(a, bb, acc4, 0, 0, 0);
        }
        int plocal = wv * 4 + quad;          // point within block (0..31), reg r = branch e
        float a0 = areaS[plocal * 4 + 0];
        float a1 = areaS[plocal * 4 + 1];
        float a2 = areaS[plocal * 4 + 2];
        float a3 = areaS[plocal * 4 + 3];
        float tot = a0 + a1 + a2 + a3;
        float r = (acc4[0] * a3 + acc4[1] * a2 + acc4[2] * a1 + acc4[3] * a0) / tot;
        if (ln15 < 3) {
            size_t pg = (size_t)blockIdx.x * 32 + plocal;
            out[pg * 3 + ln15] = r + b4[ln15];
        }
    }
}

extern "C" void kernel_launch(void* const* d_in, const int* in_sizes, int n_in,
                              void* d_out, int out_size, void* d_ws, size_t ws_size,
                              hipStream_t stream) {
    const float* inp1  = (const float*)d_in[0];
    const float* inp2  = (const float*)d_in[1];
    const float* coord = (const float*)d_in[2];
    const float* cell  = (const float*)d_in[3];
    const float* w0 = (const float*)d_in[4];
    const float* b0 = (const float*)d_in[5];
    const float* w1 = (const float*)d_in[6];
    const float* b1 = (const float*)d_in[7];
    const float* w2 = (const float*)d_in[8];
    const float* b2 = (const float*)d_in[9];
    const float* w3 = (const float*)d_in[10];
    const float* b3 = (const float*)d_in[11];
    const float* w4 = (const float*)d_in[12];
    const float* b4 = (const float*)d_in[13];
    float* out = (float*)d_out;

    unsigned short* wsp = (unsigned short*)d_ws;
    unsigned short* t1 = wsp + WTOT;
    unsigned short* t2 = t1 + NHWC_ELEMS;

    prep_all<<<PREP_BLOCKS + TRANS_BLOCKS, 256, 0, stream>>>(w0, w1, w2, w3, w4, wsp,
                                                             inp1, inp2, t1, t2);
    liif_mlp<<<8192, 512, 0, stream>>>(t1, t2, coord, cell,
                                       b0, b1, b2, b3, b4, wsp, out);
}